// Round 1
// baseline (66.487 us; speedup 1.0000x reference)
//
#include <hip/hip_runtime.h>

// Problem constants (fixed by setup_inputs)
#define NB 16        // graphs
#define NN 256       // nodes per graph
#define ND 64        // emb dim
#define NE (16*4096) // total edges

// out[b,i,j,:] = emb_table[1] if i==j else emb_table[2]  (before edge overwrite)
// float4-vectorized streaming fill of the 256 MB output.
__global__ void fill_kernel(const float* __restrict__ emb, float4* __restrict__ out) {
    const int total4 = NB * NN * NN * (ND / 4);       // 16,777,216 float4
    int idx = blockIdx.x * blockDim.x + threadIdx.x;
    const int stride = gridDim.x * blockDim.x;        // multiple of 16 -> dq loop-invariant
    const int dq = idx & (ND / 4 - 1);                // which float4 of the 64-float row
    const float4 v1 = ((const float4*)(emb + 1 * ND))[dq];  // diagonal
    const float4 v2 = ((const float4*)(emb + 2 * ND))[dq];  // disconnected
    for (; idx < total4; idx += stride) {
        const int j = (idx >> 4) & (NN - 1);
        const int i = (idx >> 12) & (NN - 1);
        out[idx] = (i == j) ? v1 : v2;
    }
}

// For each edge e: out[src*NN + (dst&255)] row <- edge_attr[e]  (64 floats)
// 16 lanes per edge, one float4 each (contiguous 256 B per edge).
__global__ void edge_kernel(const float* __restrict__ edge_attr,
                            const int* __restrict__ edge_index,
                            float* __restrict__ out) {
    const int t = blockIdx.x * blockDim.x + threadIdx.x;
    const int e = t >> 4;
    const int q = t & 15;
    if (e >= NE) return;
    const int src = edge_index[e];        // global src node id (= g*256 + ls)
    const int dst = edge_index[NE + e];   // global dst node id
    const int ld  = dst & (NN - 1);       // local col
    const long off = ((long)src * NN + ld) * ND + q * 4;
    const float4 v = *(const float4*)(edge_attr + (long)e * ND + q * 4);
    *(float4*)(out + off) = v;
}

extern "C" void kernel_launch(void* const* d_in, const int* in_sizes, int n_in,
                              void* d_out, int out_size, void* d_ws, size_t ws_size,
                              hipStream_t stream) {
    const float* edge_attr  = (const float*)d_in[0];
    const float* emb_table  = (const float*)d_in[1];
    const int*   edge_index = (const int*)d_in[2];
    // d_in[3] = batch_vec — unused (indices derivable from src/dst bit math)
    float* out = (float*)d_out;

    fill_kernel<<<2048, 256, 0, stream>>>(emb_table, (float4*)out);

    const int edge_threads = NE * 16;  // 1,048,576
    edge_kernel<<<edge_threads / 256, 256, 0, stream>>>(edge_attr, edge_index, out);
}